// Round 1
// baseline (226.650 us; speedup 1.0000x reference)
//
#include <hip/hip_runtime.h>

// WaveConv3d: 2-level 3D Haar DWT + low-frequency spectral conv on the 8
// level-2 subbands + inverse DWT, algebraically reduced to:
//   s_k   = signed 4x4x4 block-reduce of x            (8 subbands, 16^3)
//   ds_k  = spectralconv_k(s_k) - s_k                 (sparse-DFT path)
//   out   = x + (1/8) * sum_k sign_k(cell) * ds_k     (block scatter)

__constant__ float C16c[16] = {
  1.0f, 0.92387953251128675f, 0.70710678118654752f, 0.38268343236508977f,
  0.0f, -0.38268343236508977f, -0.70710678118654752f, -0.92387953251128675f,
  -1.0f, -0.92387953251128675f, -0.70710678118654752f, -0.38268343236508977f,
  0.0f, 0.38268343236508977f, 0.70710678118654752f, 0.92387953251128675f
};
__constant__ float S16c[16] = {
  0.0f, 0.38268343236508977f, 0.70710678118654752f, 0.92387953251128675f,
  1.0f, 0.92387953251128675f, 0.70710678118654752f, 0.38268343236508977f,
  0.0f, -0.38268343236508977f, -0.70710678118654752f, -0.92387953251128675f,
  -1.0f, -0.92387953251128675f, -0.70710678118654752f, -0.38268343236508977f
};
__constant__ int KYv[6] = {0, 1, 2, 13, 14, 15};

// ---------------------------------------------------------------------------
// K1: x (4,64,64,64,64) -> 8 subbands s[k][b][c][16^3], k = dx*4+dy*2+dz
// Each thread owns one 4x4x4 block: 16 float4 loads, 2x2x2 Hadamard, 8 writes.
__global__ __launch_bounds__(256) void k_analyze(const float* __restrict__ x,
                                                 float* __restrict__ s) {
  unsigned tid = blockIdx.x * 256u + threadIdx.x;
  unsigned pz = tid & 15u, py = (tid >> 4) & 15u, px = (tid >> 8) & 15u;
  unsigned bc = tid >> 12;
  const float* xp = x + ((size_t)bc << 18);
  float t[2][2][2] = {{{0.f, 0.f}, {0.f, 0.f}}, {{0.f, 0.f}, {0.f, 0.f}}};
#pragma unroll
  for (int i = 0; i < 4; i++)
#pragma unroll
    for (int j = 0; j < 4; j++) {
      const float4 v = *(const float4*)(xp + (size_t)(((4u * px + i) << 6) + (4u * py + j)) * 64u + 4u * pz);
      t[i >> 1][j >> 1][0] += v.x + v.y;
      t[i >> 1][j >> 1][1] += v.z + v.w;
    }
  float tz[2][2][2], ty[2][2][2];
#pragma unroll
  for (int i = 0; i < 2; i++)
#pragma unroll
    for (int j = 0; j < 2; j++) {
      tz[i][j][0] = t[i][j][0] + t[i][j][1];
      tz[i][j][1] = t[i][j][0] - t[i][j][1];
    }
#pragma unroll
  for (int i = 0; i < 2; i++)
#pragma unroll
    for (int dz = 0; dz < 2; dz++) {
      ty[i][0][dz] = tz[i][0][dz] + tz[i][1][dz];
      ty[i][1][dz] = tz[i][0][dz] - tz[i][1][dz];
    }
  unsigned p = tid & 4095u;
  size_t base = (size_t)bc * 4096u + p;
#pragma unroll
  for (int dx = 0; dx < 2; dx++)
#pragma unroll
    for (int dy = 0; dy < 2; dy++)
#pragma unroll
      for (int dz = 0; dz < 2; dz++) {
        float r = (dx ? (ty[0][dy][dz] - ty[1][dy][dz]) : (ty[0][dy][dz] + ty[1][dy][dz])) * 0.125f;
        int k = dx * 4 + dy * 2 + dz;
        s[((size_t)k << 20) + base] = r;
      }
}

// ---------------------------------------------------------------------------
// K2a: forward sparse DFT. One WG per (k,b,i): 16^3 -> 108 complex coeffs
// at kx,ky in {0,1,2,13,14,15}, kz in {0,1,2}. in_hat[wg][108].
__global__ __launch_bounds__(256) void k_fwd(const float* __restrict__ s,
                                             float2* __restrict__ ih) {
  __shared__ float xl[16 * 16 * 17];
  __shared__ float2 fz[3][16][17];
  __shared__ float2 g[16][6][3];
  unsigned tid = threadIdx.x;
  const float* sp = s + ((size_t)blockIdx.x << 12);
  for (unsigned t = tid; t < 4096u; t += 256u) {
    unsigned z = t & 15u, xy = t >> 4;
    xl[xy * 17u + z] = sp[t];
  }
  __syncthreads();
  {  // z-transform: (x,y) per thread, 3 kz outputs
    unsigned y = tid & 15u, xx = tid >> 4;
    const float* row = &xl[(xx * 16u + y) * 17u];
#pragma unroll
    for (int kz = 0; kz < 3; kz++) {
      float re = 0.f, im = 0.f;
#pragma unroll
      for (int nz = 0; nz < 16; nz++) {
        float vv = row[nz];
        int t16 = (kz * nz) & 15;
        re += vv * C16c[t16];
        im -= vv * S16c[t16];
      }
      fz[kz][xx][y] = make_float2(re, im);
    }
  }
  __syncthreads();
  for (unsigned idx = tid; idx < 288u; idx += 256u) {  // y-transform
    unsigned kz = idx % 3u, kyi = (idx / 3u) % 6u, xx = idx / 18u;
    int ky = KYv[kyi];
    float re = 0.f, im = 0.f;
#pragma unroll
    for (int ny = 0; ny < 16; ny++) {
      float2 vv = fz[kz][xx][ny];
      int t16 = (ky * ny) & 15;
      float c = C16c[t16], sn = S16c[t16];
      re += vv.x * c + vv.y * sn;   // v * exp(-i th)
      im += vv.y * c - vv.x * sn;
    }
    g[xx][kyi][kz] = make_float2(re, im);
  }
  __syncthreads();
  if (tid < 108u) {  // x-transform
    unsigned kz = tid % 3u, kyi = (tid / 3u) % 6u, kxi = tid / 18u;
    int kx = KYv[kxi];
    float re = 0.f, im = 0.f;
#pragma unroll
    for (int nx = 0; nx < 16; nx++) {
      float2 vv = g[nx][kyi][kz];
      int t16 = (kx * nx) & 15;
      float c = C16c[t16], sn = S16c[t16];
      re += vv.x * c + vv.y * sn;
      im += vv.y * c - vv.x * sn;
    }
    ih[(size_t)blockIdx.x * 108u + tid] = make_float2(re, im);
  }
}

// ---------------------------------------------------------------------------
// K2b: per-frequency channel mix. WG = (k, corner, o-block of 4); 128 thr =
// (b in 4) x (f in 27, 5 idle). out_hat[b,o,f] = sum_i in_hat[b,i,f]*w[i,o,f].
__global__ __launch_bounds__(128) void k_mix(const float2* __restrict__ w2,
                                             const float2* __restrict__ ih,
                                             float2* __restrict__ oh) {
  unsigned ob = blockIdx.x & 15u;
  unsigned corner = (blockIdx.x >> 4) & 3u;
  unsigned k = blockIdx.x >> 6;
  unsigned b = threadIdx.x >> 5;
  unsigned f = threadIdx.x & 31u;
  if (f >= 27u) return;
  unsigned kz = f % 3u, kyl = (f / 3u) % 3u, kxl = f / 9u;
  unsigned fg = ((kxl + 3u * (corner & 1u)) * 6u + (kyl + 3u * (corner >> 1))) * 3u + kz;
  const float2* ip = ih + (size_t)((k * 4u + b) * 64u) * 108u + fg;
  const float2* wp = w2 + ((size_t)((k * 4u + corner) * 64u) * 64u + ob * 4u) * 27u + f;
  float2 acc[4];
#pragma unroll
  for (int oo = 0; oo < 4; oo++) acc[oo] = make_float2(0.f, 0.f);
  for (unsigned i = 0; i < 64u; i++) {
    float2 a = ip[(size_t)i * 108u];
    const float2* wq = wp + (size_t)i * (64u * 27u);
#pragma unroll
    for (int oo = 0; oo < 4; oo++) {
      float2 ww = wq[(size_t)oo * 27u];
      acc[oo].x += a.x * ww.x - a.y * ww.y;
      acc[oo].y += a.x * ww.y + a.y * ww.x;
    }
  }
#pragma unroll
  for (int oo = 0; oo < 4; oo++)
    oh[(size_t)((k * 4u + b) * 64u + ob * 4u + oo) * 108u + fg] = acc[oo];
}

// ---------------------------------------------------------------------------
// K2c: inverse sparse DFT + subtract s -> delta[b][o][k][16^3].
// irfft semantics: only Re(u[kz=0]) contributes (imag of bin 0 is ignored).
__global__ __launch_bounds__(256) void k_inv(const float2* __restrict__ oh,
                                             const float* __restrict__ s,
                                             float* __restrict__ delta) {
  __shared__ float2 hh[108];
  __shared__ float2 gx[16][6][3];
  __shared__ float2 u[3][16][17];
  unsigned tid = threadIdx.x;
  if (tid < 108u) hh[tid] = oh[(size_t)blockIdx.x * 108u + tid];
  __syncthreads();
  for (unsigned idx = tid; idx < 288u; idx += 256u) {  // x-inverse
    unsigned kz = idx % 3u, kyi = (idx / 3u) % 6u, nx = idx / 18u;
    float re = 0.f, im = 0.f;
#pragma unroll
    for (int kxi = 0; kxi < 6; kxi++) {
      float2 vv = hh[kxi * 18 + kyi * 3 + kz];
      int t16 = (KYv[kxi] * (int)nx) & 15;
      float c = C16c[t16], sn = S16c[t16];
      re += vv.x * c - vv.y * sn;   // v * exp(+i th)
      im += vv.x * sn + vv.y * c;
    }
    gx[nx][kyi][kz] = make_float2(re, im);
  }
  __syncthreads();
  {  // y-inverse
    unsigned ny = tid & 15u, nx = tid >> 4;
#pragma unroll
    for (int kz = 0; kz < 3; kz++) {
      float re = 0.f, im = 0.f;
#pragma unroll
      for (int kyi = 0; kyi < 6; kyi++) {
        float2 vv = gx[nx][kyi][kz];
        int t16 = (KYv[kyi] * (int)ny) & 15;
        float c = C16c[t16], sn = S16c[t16];
        re += vv.x * c - vv.y * sn;
        im += vv.x * sn + vv.y * c;
      }
      u[kz][nx][ny] = make_float2(re, im);
    }
  }
  __syncthreads();
  {  // z-inverse (irfft) + delta
    unsigned ny = tid & 15u, nx = tid >> 4;
    float2 u0 = u[0][nx][ny], u1 = u[1][nx][ny], u2 = u[2][nx][ny];
    unsigned bo = blockIdx.x & 255u;
    unsigned k = blockIdx.x >> 8;
    unsigned p = nx * 256u + ny * 16u;
    const float* sp = s + ((size_t)blockIdx.x << 12) + p;
    float* dp = delta + (((size_t)bo * 8u + k) << 12) + p;
    const float inv = 1.0f / 4096.0f;
#pragma unroll
    for (int nz = 0; nz < 16; nz++) {
      float c1 = C16c[nz], s1 = S16c[nz];
      int t2 = (2 * nz) & 15;
      float c2 = C16c[t2], s2 = S16c[t2];
      float val = inv * (u0.x + 2.f * (u1.x * c1 - u1.y * s1) + 2.f * (u2.x * c2 - u2.y * s2));
      dp[nz] = val - sp[nz];
    }
  }
}

// ---------------------------------------------------------------------------
// K3: out = x + (1/8) * sum_k sign_k(cell) * delta_k. Thread = 4 z-elements.
__global__ __launch_bounds__(256) void k_synth(const float* __restrict__ x,
                                               const float* __restrict__ delta,
                                               float* __restrict__ out) {
  unsigned tid = blockIdx.x * 256u + threadIdx.x;
  float4 v = *(const float4*)(x + ((size_t)tid << 2));
  unsigned z4 = tid & 15u;          // == pz
  unsigned y = (tid >> 4) & 63u;
  unsigned xx = (tid >> 10) & 63u;
  unsigned bc = tid >> 16;
  unsigned p = ((xx >> 2) << 8) + ((y >> 2) << 4) + z4;
  const float* dp = delta + ((size_t)bc << 15) + p;
  unsigned i = (xx >> 1) & 1u, j = (y >> 1) & 1u;
  float a0 = 0.f, a1 = 0.f;
#pragma unroll
  for (int k = 0; k < 8; k++) {
    float d = dp[(size_t)k << 12];
    unsigned sxy = (i & (unsigned)(k >> 2)) ^ (j & (unsigned)((k >> 1) & 1));
    float sd = sxy ? -d : d;
    a0 += sd;
    a1 += (k & 1) ? -sd : sd;
  }
  v.x += 0.125f * a0;
  v.y += 0.125f * a0;
  v.z += 0.125f * a1;
  v.w += 0.125f * a1;
  *(float4*)(out + ((size_t)tid << 2)) = v;
}

extern "C" void kernel_launch(void* const* d_in, const int* in_sizes, int n_in,
                              void* d_out, int out_size, void* d_ws, size_t ws_size,
                              hipStream_t stream) {
  const float* x = (const float*)d_in[0];
  const float* w = (const float*)d_in[1];
  float* out = (float*)d_out;

  const size_t S_FLOATS = 8ull * 4 * 64 * 4096;   // 8,388,608 (32 MiB)
  const size_t HAT_F2 = 2048ull * 108;            // 221,184 float2 (1.7 MiB)
  const size_t S_BYTES = S_FLOATS * 4;
  const size_t HAT_BYTES = HAT_F2 * 8;

  float *s, *delta;
  float2 *ih, *oh;
  char* ws = (char*)d_ws;
  if (ws_size >= 2 * S_BYTES + 2 * HAT_BYTES) {
    s = (float*)ws;
    delta = (float*)(ws + S_BYTES);
    ih = (float2*)(ws + 2 * S_BYTES);
    oh = ih + HAT_F2;
  } else {
    // d_out doubles as dead scratch: s & hats live there; k_synth only reads
    // x and delta(ws) while overwriting all of d_out, so no hazard.
    s = (float*)d_out;
    ih = (float2*)((char*)d_out + S_BYTES);
    oh = ih + HAT_F2;
    delta = (float*)ws;  // needs 32 MiB
  }

  k_analyze<<<4096, 256, 0, stream>>>(x, s);
  k_fwd<<<2048, 256, 0, stream>>>(s, ih);
  k_mix<<<512, 128, 0, stream>>>((const float2*)w, ih, oh);
  k_inv<<<2048, 256, 0, stream>>>(oh, s, delta);
  k_synth<<<65536, 256, 0, stream>>>(x, delta, out);
}

// Round 2
// 213.594 us; speedup vs baseline: 1.0611x; 1.0611x over previous
//
#include <hip/hip_runtime.h>

// WaveConv3d: 2-level 3D Haar DWT + low-frequency spectral conv on the 8
// level-2 subbands + inverse DWT, algebraically reduced to:
//   s_k    = signed 4x4x4 block-reduce of x           (8 subbands, 16^3)
//   out    = x - mean_{2x2x2}(x) + (1/8) sum_k sign_k(cell) * idft(conv_k)
// (the "- s_k" subtraction term collapses to the local 2x2x2 mean of x).

__constant__ float C16c[16] = {
  1.0f, 0.92387953251128675f, 0.70710678118654752f, 0.38268343236508977f,
  0.0f, -0.38268343236508977f, -0.70710678118654752f, -0.92387953251128675f,
  -1.0f, -0.92387953251128675f, -0.70710678118654752f, -0.38268343236508977f,
  0.0f, 0.38268343236508977f, 0.70710678118654752f, 0.92387953251128675f
};
__constant__ float S16c[16] = {
  0.0f, 0.38268343236508977f, 0.70710678118654752f, 0.92387953251128675f,
  1.0f, 0.92387953251128675f, 0.70710678118654752f, 0.38268343236508977f,
  0.0f, -0.38268343236508977f, -0.70710678118654752f, -0.92387953251128675f,
  -1.0f, -0.92387953251128675f, -0.70710678118654752f, -0.38268343236508977f
};
__constant__ int KYv[6] = {0, 1, 2, 13, 14, 15};

// ---------------------------------------------------------------------------
// K1: x (4,64,64,64,64) -> 8 subbands s[k][bc][16^3], k = dx*4+dy*2+dz
__global__ __launch_bounds__(256) void k_analyze(const float* __restrict__ x,
                                                 float* __restrict__ s) {
  unsigned tid = blockIdx.x * 256u + threadIdx.x;
  unsigned pz = tid & 15u, py = (tid >> 4) & 15u, px = (tid >> 8) & 15u;
  unsigned bc = tid >> 12;
  const float* xp = x + ((size_t)bc << 18);
  float t[2][2][2] = {{{0.f, 0.f}, {0.f, 0.f}}, {{0.f, 0.f}, {0.f, 0.f}}};
#pragma unroll
  for (int i = 0; i < 4; i++)
#pragma unroll
    for (int j = 0; j < 4; j++) {
      const float4 v = *(const float4*)(xp + (size_t)(((4u * px + i) << 6) + (4u * py + j)) * 64u + 4u * pz);
      t[i >> 1][j >> 1][0] += v.x + v.y;
      t[i >> 1][j >> 1][1] += v.z + v.w;
    }
  float tz[2][2][2], ty[2][2][2];
#pragma unroll
  for (int i = 0; i < 2; i++)
#pragma unroll
    for (int j = 0; j < 2; j++) {
      tz[i][j][0] = t[i][j][0] + t[i][j][1];
      tz[i][j][1] = t[i][j][0] - t[i][j][1];
    }
#pragma unroll
  for (int i = 0; i < 2; i++)
#pragma unroll
    for (int dz = 0; dz < 2; dz++) {
      ty[i][0][dz] = tz[i][0][dz] + tz[i][1][dz];
      ty[i][1][dz] = tz[i][0][dz] - tz[i][1][dz];
    }
  unsigned p = tid & 4095u;
  size_t base = (size_t)bc * 4096u + p;
#pragma unroll
  for (int dx = 0; dx < 2; dx++)
#pragma unroll
    for (int dy = 0; dy < 2; dy++)
#pragma unroll
      for (int dz = 0; dz < 2; dz++) {
        float r = (dx ? (ty[0][dy][dz] - ty[1][dy][dz]) : (ty[0][dy][dz] + ty[1][dy][dz])) * 0.125f;
        int k = dx * 4 + dy * 2 + dz;
        s[((size_t)k << 20) + base] = r;
      }
}

// ---------------------------------------------------------------------------
// K2a: forward sparse DFT. One WG per (k,bc): 16^3 -> 108 coeffs.
__global__ __launch_bounds__(256) void k_fwd(const float* __restrict__ s,
                                             float2* __restrict__ ih) {
  __shared__ float xl[16 * 16 * 17];
  __shared__ float2 fz[3][16][17];
  __shared__ float2 g[16][6][3];
  unsigned tid = threadIdx.x;
  const float* sp = s + ((size_t)blockIdx.x << 12);
  for (unsigned t = tid; t < 4096u; t += 256u) {
    unsigned z = t & 15u, xy = t >> 4;
    xl[xy * 17u + z] = sp[t];
  }
  __syncthreads();
  {  // z-transform
    unsigned y = tid & 15u, xx = tid >> 4;
    const float* row = &xl[(xx * 16u + y) * 17u];
#pragma unroll
    for (int kz = 0; kz < 3; kz++) {
      float re = 0.f, im = 0.f;
#pragma unroll
      for (int nz = 0; nz < 16; nz++) {
        float vv = row[nz];
        int t16 = (kz * nz) & 15;
        re += vv * C16c[t16];
        im -= vv * S16c[t16];
      }
      fz[kz][xx][y] = make_float2(re, im);
    }
  }
  __syncthreads();
  for (unsigned idx = tid; idx < 288u; idx += 256u) {  // y-transform
    unsigned kz = idx % 3u, kyi = (idx / 3u) % 6u, xx = idx / 18u;
    int ky = KYv[kyi];
    float re = 0.f, im = 0.f;
#pragma unroll
    for (int ny = 0; ny < 16; ny++) {
      float2 vv = fz[kz][xx][ny];
      int t16 = (ky * ny) & 15;
      float c = C16c[t16], sn = S16c[t16];
      re += vv.x * c + vv.y * sn;
      im += vv.y * c - vv.x * sn;
    }
    g[xx][kyi][kz] = make_float2(re, im);
  }
  __syncthreads();
  if (tid < 108u) {  // x-transform
    unsigned kz = tid % 3u, kyi = (tid / 3u) % 6u, kxi = tid / 18u;
    int kx = KYv[kxi];
    float re = 0.f, im = 0.f;
#pragma unroll
    for (int nx = 0; nx < 16; nx++) {
      float2 vv = g[nx][kyi][kz];
      int t16 = (kx * nx) & 15;
      float c = C16c[t16], sn = S16c[t16];
      re += vv.x * c + vv.y * sn;
      im += vv.y * c - vv.x * sn;
    }
    ih[(size_t)blockIdx.x * 108u + tid] = make_float2(re, im);
  }
}

// ---------------------------------------------------------------------------
// K2b: per-frequency channel mix.
__global__ __launch_bounds__(128) void k_mix(const float2* __restrict__ w2,
                                             const float2* __restrict__ ih,
                                             float2* __restrict__ oh) {
  unsigned ob = blockIdx.x & 15u;
  unsigned corner = (blockIdx.x >> 4) & 3u;
  unsigned k = blockIdx.x >> 6;
  unsigned b = threadIdx.x >> 5;
  unsigned f = threadIdx.x & 31u;
  if (f >= 27u) return;
  unsigned kz = f % 3u, kyl = (f / 3u) % 3u, kxl = f / 9u;
  unsigned fg = ((kxl + 3u * (corner & 1u)) * 6u + (kyl + 3u * (corner >> 1))) * 3u + kz;
  const float2* ip = ih + (size_t)((k * 4u + b) * 64u) * 108u + fg;
  const float2* wp = w2 + ((size_t)((k * 4u + corner) * 64u) * 64u + ob * 4u) * 27u + f;
  float2 acc[4];
#pragma unroll
  for (int oo = 0; oo < 4; oo++) acc[oo] = make_float2(0.f, 0.f);
  for (unsigned i = 0; i < 64u; i++) {
    float2 a = ip[(size_t)i * 108u];
    const float2* wq = wp + (size_t)i * (64u * 27u);
#pragma unroll
    for (int oo = 0; oo < 4; oo++) {
      float2 ww = wq[(size_t)oo * 27u];
      acc[oo].x += a.x * ww.x - a.y * ww.y;
      acc[oo].y += a.x * ww.y + a.y * ww.x;
    }
  }
#pragma unroll
  for (int oo = 0; oo < 4; oo++)
    oh[(size_t)((k * 4u + b) * 64u + ob * 4u + oo) * 108u + fg] = acc[oo];
}

// ---------------------------------------------------------------------------
// K3: fused inverse sparse DFT + synthesis.
// WG = (bo, slab): slab = nx (4 X-planes). Phase 1 builds
// W[m][ny][nz] = sum_k (-1)^{popc(k&m)} * idft(conv_k)[nx,ny,nz] in LDS.
// Phase 2 streams: out = x - mean2x2x2(x) + 0.125 * W[cell][ny][nz].
__global__ __launch_bounds__(256) void k_invsynth(const float2* __restrict__ oh,
                                                  const float* __restrict__ x,
                                                  float* __restrict__ out) {
  __shared__ float2 hh[8][108];
  __shared__ float2 gx[8][6][3];   // [k][kyi][kz]
  __shared__ float2 uu[8][3][16];  // [k][kz][ny]
  __shared__ float W[8][16][16];   // [m][ny][nz]
  unsigned tid = threadIdx.x;
  unsigned slab = blockIdx.x & 15u;  // nx
  unsigned bo = blockIdx.x >> 4;     // b*64 + o
  for (unsigned i = tid; i < 864u; i += 256u) {
    unsigned k = i / 108u, f = i - k * 108u;
    ((float2*)hh)[i] = oh[(size_t)((k << 8) + bo) * 108u + f];
  }
  __syncthreads();
  if (tid < 144u) {  // x-inverse at nx = slab
    unsigned k = tid / 18u, r = tid - k * 18u;  // r = kyi*3+kz
    float re = 0.f, im = 0.f;
#pragma unroll
    for (int kxi = 0; kxi < 6; kxi++) {
      float2 v = hh[k][kxi * 18 + r];
      int t16 = (KYv[kxi] * (int)slab) & 15;
      float c = C16c[t16], sn = S16c[t16];
      re += v.x * c - v.y * sn;
      im += v.x * sn + v.y * c;
    }
    ((float2*)gx)[tid] = make_float2(re, im);
  }
  __syncthreads();
  for (unsigned i = tid; i < 384u; i += 256u) {  // y-inverse
    unsigned k = i / 48u, rem = i - k * 48u;
    unsigned kz = rem >> 4, ny = rem & 15u;
    float re = 0.f, im = 0.f;
#pragma unroll
    for (int kyi = 0; kyi < 6; kyi++) {
      float2 v = gx[k][kyi][kz];
      int t16 = (KYv[kyi] * (int)ny) & 15;
      float c = C16c[t16], sn = S16c[t16];
      re += v.x * c - v.y * sn;
      im += v.x * sn + v.y * c;
    }
    uu[k][kz][ny] = make_float2(re, im);
  }
  __syncthreads();
  {  // z-inverse + signed Hadamard over k
    unsigned ny = tid >> 4, nz = tid & 15u;
    float c1 = C16c[nz], s1 = S16c[nz];
    int t2 = (2 * nz) & 15;
    float c2 = C16c[t2], s2 = S16c[t2];
    float val[8];
#pragma unroll
    for (int k = 0; k < 8; k++) {
      float2 u0 = uu[k][0][ny], u1 = uu[k][1][ny], u2 = uu[k][2][ny];
      val[k] = (u0.x + 2.f * (u1.x * c1 - u1.y * s1) + 2.f * (u2.x * c2 - u2.y * s2)) * (1.f / 4096.f);
    }
#pragma unroll
    for (int st = 1; st < 8; st <<= 1)
#pragma unroll
      for (int i2 = 0; i2 < 8; i2++)
        if (!(i2 & st)) {
          float a = val[i2], b = val[i2 | st];
          val[i2] = a + b;
          val[i2 | st] = a - b;
        }
#pragma unroll
    for (int m = 0; m < 8; m++) W[m][ny][nz] = val[m];
  }
  __syncthreads();
  // Phase 2: streaming. lane = z4 | y0<<4 | x0<<5 ; w = tid>>6.
  unsigned z4 = tid & 15u;
  unsigned y0 = (tid >> 4) & 1u;
  unsigned x0 = (tid >> 5) & 1u;
  unsigned w = tid >> 6;
  const float* xp = x + ((size_t)bo << 18);
  float* op = out + ((size_t)bo << 18);
#pragma unroll 4
  for (unsigned it = 0; it < 16u; ++it) {
    unsigned idx = w + (it << 2);  // 0..63
    unsigned lx1 = idx & 1u;
    unsigned yh = idx >> 1;        // 0..31
    unsigned X = (slab << 2) + (lx1 << 1) + x0;
    unsigned Y = (yh << 1) + y0;
    size_t off = ((((size_t)X << 6) + Y) << 6) + (z4 << 2);
    float4 v = *(const float4*)(xp + off);
    float h0 = v.x + v.y, h1 = v.z + v.w;
    h0 += __shfl_xor(h0, 16);
    h1 += __shfl_xor(h1, 16);
    h0 += __shfl_xor(h0, 32);
    h1 += __shfl_xor(h1, 32);
    float m0 = (h0 + h1) * 0.f + h0 * 0.125f;  // keep simple: m0 = h0/8
    float m1 = h1 * 0.125f;
    unsigned ny = yh >> 1, nz = z4;
    unsigned mm = (lx1 << 2) | ((yh & 1u) << 1);
    float c0 = 0.125f * W[mm][ny][nz] - m0;
    float c1 = 0.125f * W[mm | 1u][ny][nz] - m1;
    v.x += c0;
    v.y += c0;
    v.z += c1;
    v.w += c1;
    *(float4*)(op + off) = v;
  }
}

extern "C" void kernel_launch(void* const* d_in, const int* in_sizes, int n_in,
                              void* d_out, int out_size, void* d_ws, size_t ws_size,
                              hipStream_t stream) {
  const float* x = (const float*)d_in[0];
  const float* w = (const float*)d_in[1];
  float* out = (float*)d_out;

  const size_t S_FLOATS = 8ull * 256 * 4096;  // 8,388,608 (32 MiB)
  const size_t HAT_F2 = 2048ull * 108;        // 221,184 float2 (1.7 MiB)
  const size_t S_BYTES = S_FLOATS * 4;
  const size_t HAT_BYTES = HAT_F2 * 8;

  float* s;
  float2 *ih, *oh;
  char* ws = (char*)d_ws;
  if (ws_size >= S_BYTES + 2 * HAT_BYTES) {
    s = (float*)ws;
    ih = (float2*)(ws + S_BYTES);
    oh = ih + HAT_F2;
  } else {
    // d_out doubles as dead scratch for s and ih (consumed before k_invsynth
    // overwrites d_out); oh must survive into k_invsynth -> keep in ws.
    s = (float*)d_out;
    ih = (float2*)((char*)d_out + S_BYTES);
    oh = (float2*)ws;  // needs 1.7 MiB
  }

  k_analyze<<<4096, 256, 0, stream>>>(x, s);
  k_fwd<<<2048, 256, 0, stream>>>(s, ih);
  k_mix<<<512, 128, 0, stream>>>((const float2*)w, ih, oh);
  k_invsynth<<<4096, 256, 0, stream>>>(oh, x, out);
}

// Round 3
// 207.419 us; speedup vs baseline: 1.0927x; 1.0298x over previous
//
#include <hip/hip_runtime.h>

// WaveConv3d: 2-level 3D Haar DWT + low-freq spectral conv on the 8 level-2
// subbands + inverse DWT, algebraically reduced to:
//   s_k    = signed 4x4x4 block-reduce of x           (8 subbands, 16^3)
//   ih     = sparse 3D DFT of s_k (6x6x3 freqs)       (fused with analyze)
//   oh     = per-frequency 64->64 channel mix
//   out    = x - mean_{2x2x2}(x) + (1/8) sum_k sign_k(cell) * idft(oh_k)

__constant__ float C16c[16] = {
  1.0f, 0.92387953251128675f, 0.70710678118654752f, 0.38268343236508977f,
  0.0f, -0.38268343236508977f, -0.70710678118654752f, -0.92387953251128675f,
  -1.0f, -0.92387953251128675f, -0.70710678118654752f, -0.38268343236508977f,
  0.0f, 0.38268343236508977f, 0.70710678118654752f, 0.92387953251128675f
};
__constant__ float S16c[16] = {
  0.0f, 0.38268343236508977f, 0.70710678118654752f, 0.92387953251128675f,
  1.0f, 0.92387953251128675f, 0.70710678118654752f, 0.38268343236508977f,
  0.0f, -0.38268343236508977f, -0.70710678118654752f, -0.92387953251128675f,
  -1.0f, -0.92387953251128675f, -0.70710678118654752f, -0.38268343236508977f
};
__constant__ int KYv[6] = {0, 1, 2, 13, 14, 15};

// ---------------------------------------------------------------------------
// K1: fused analyze + z-DFT + y-DFT. WG = (bc, px): 256 thr = (py,pz).
// Writes g[(bc*16+px)*144 + k*18 + kyi*3 + kz]  (4.7 MB total).
__global__ __launch_bounds__(256) void k_front(const float* __restrict__ x,
                                               float2* __restrict__ g) {
  __shared__ float sm[8][16][17];
  __shared__ float2 fz[8][3][17];
  unsigned tid = threadIdx.x;
  unsigned px = blockIdx.x & 15u;
  unsigned bc = blockIdx.x >> 4;
  unsigned pz = tid & 15u, py = tid >> 4;
  const float* xp = x + ((size_t)bc << 18);
  float t[2][2][2] = {{{0.f, 0.f}, {0.f, 0.f}}, {{0.f, 0.f}, {0.f, 0.f}}};
#pragma unroll
  for (int i = 0; i < 4; i++)
#pragma unroll
    for (int j = 0; j < 4; j++) {
      const float4 v = *(const float4*)(xp + (size_t)(((4u * px + i) << 6) + (4u * py + j)) * 64u + 4u * pz);
      t[i >> 1][j >> 1][0] += v.x + v.y;
      t[i >> 1][j >> 1][1] += v.z + v.w;
    }
  float tz[2][2][2], ty[2][2][2];
#pragma unroll
  for (int i = 0; i < 2; i++)
#pragma unroll
    for (int j = 0; j < 2; j++) {
      tz[i][j][0] = t[i][j][0] + t[i][j][1];
      tz[i][j][1] = t[i][j][0] - t[i][j][1];
    }
#pragma unroll
  for (int i = 0; i < 2; i++)
#pragma unroll
    for (int dz = 0; dz < 2; dz++) {
      ty[i][0][dz] = tz[i][0][dz] + tz[i][1][dz];
      ty[i][1][dz] = tz[i][0][dz] - tz[i][1][dz];
    }
#pragma unroll
  for (int dx = 0; dx < 2; dx++)
#pragma unroll
    for (int dy = 0; dy < 2; dy++)
#pragma unroll
      for (int dz = 0; dz < 2; dz++) {
        float r = (dx ? (ty[0][dy][dz] - ty[1][dy][dz]) : (ty[0][dy][dz] + ty[1][dy][dz])) * 0.125f;
        sm[dx * 4 + dy * 2 + dz][py][pz] = r;
      }
  __syncthreads();
  if (tid < 128u) {  // z-DFT: thread = (k, ny=py), 3 kz outputs
    unsigned k = tid >> 4, y = tid & 15u;
    const float* row = &sm[k][y][0];
#pragma unroll
    for (int kz = 0; kz < 3; kz++) {
      float re = 0.f, im = 0.f;
#pragma unroll
      for (int nz = 0; nz < 16; nz++) {
        float vv = row[nz];
        int t16 = (kz * nz) & 15;
        re += vv * C16c[t16];
        im -= vv * S16c[t16];
      }
      fz[k][kz][y] = make_float2(re, im);
    }
  }
  __syncthreads();
  if (tid < 144u) {  // y-DFT: thread = (k, kyi, kz)
    unsigned k = tid / 18u, r = tid - k * 18u;
    unsigned kyi = r / 3u, kz = r - kyi * 3u;
    int ky = KYv[kyi];
    float re = 0.f, im = 0.f;
#pragma unroll
    for (int ny = 0; ny < 16; ny++) {
      float2 vv = fz[k][kz][ny];
      int t16 = (ky * ny) & 15;
      float c = C16c[t16], sn = S16c[t16];
      re += vv.x * c + vv.y * sn;
      im += vv.y * c - vv.x * sn;
    }
    g[(size_t)blockIdx.x * 144u + tid] = make_float2(re, im);
  }
}

// ---------------------------------------------------------------------------
// K2: x-axis DFT. WG = (k, bc): 128 thr, 108 active = (kxi, kyi, kz).
__global__ __launch_bounds__(128) void k_xdft(const float2* __restrict__ g,
                                              float2* __restrict__ ih) {
  unsigned tid = threadIdx.x;
  if (tid >= 108u) return;
  unsigned bc = blockIdx.x & 255u;
  unsigned k = blockIdx.x >> 8;
  unsigned kxi = tid / 18u, r = tid - kxi * 18u;
  const float2* gp = g + (size_t)bc * 2304u + k * 18u + r;
  int kx = KYv[kxi];
  float re = 0.f, im = 0.f;
#pragma unroll
  for (int nx = 0; nx < 16; nx++) {
    float2 vv = gp[(size_t)nx * 144u];
    int t16 = (kx * nx) & 15;
    float c = C16c[t16], sn = S16c[t16];
    re += vv.x * c + vv.y * sn;
    im += vv.y * c - vv.x * sn;
  }
  ih[(size_t)blockIdx.x * 108u + tid] = make_float2(re, im);
}

// ---------------------------------------------------------------------------
// K3: weight transpose  wt[((kc*27+f)*64+i)*64+o] = w[((kc*64+i)*64+o)*27+f].
// WG = (kc, i-block of 4): both load and store coalesced via LDS.
__global__ __launch_bounds__(256) void k_wtr(const float2* __restrict__ w2,
                                             float2* __restrict__ wt) {
  __shared__ float2 l[4 * 64 * 27];  // 55296 B
  unsigned tid = threadIdx.x;
  unsigned ib = blockIdx.x & 15u;
  unsigned kc = blockIdx.x >> 4;
  const float2* src = w2 + ((size_t)kc * 64u + ib * 4u) * 64u * 27u;
#pragma unroll
  for (int q = 0; q < 27; q++) l[q * 256 + tid] = src[(size_t)q * 256u + tid];
  __syncthreads();
  float2* dst = wt + (size_t)kc * 110592u + ib * 256u;
  unsigned i = tid >> 6, o = tid & 63u;
#pragma unroll
  for (int f = 0; f < 27; f++)
    dst[(size_t)f * 4096u + tid] = l[(i * 64u + o) * 27u + f];
}

// ---------------------------------------------------------------------------
// K4: per-frequency channel mix. WG = (kc, f): 256 thr = (b, o).
// Weight stream fully coalesced (512 B / wave-instr), read exactly once.
__global__ __launch_bounds__(256) void k_mix2(const float2* __restrict__ wt,
                                              const float2* __restrict__ ih,
                                              float2* __restrict__ oh) {
  __shared__ float2 inl[4][64];
  unsigned tid = threadIdx.x;
  unsigned f = blockIdx.x % 27u;
  unsigned kc = blockIdx.x / 27u;
  unsigned k = kc >> 2, corner = kc & 3u;
  unsigned kz = f % 3u, kyl = (f / 3u) % 3u, kxl = f / 9u;
  unsigned fg = ((kxl + 3u * (corner & 1u)) * 6u + (kyl + 3u * (corner >> 1))) * 3u + kz;
  {
    unsigned b = tid >> 6, i = tid & 63u;
    inl[b][i] = ih[(size_t)(k * 256u + b * 64u + i) * 108u + fg];
  }
  __syncthreads();
  unsigned b = tid >> 6, o = tid & 63u;
  const float2* wp = wt + ((size_t)kc * 27u + f) * 4096u + o;
  float2 acc = make_float2(0.f, 0.f);
#pragma unroll 8
  for (unsigned i = 0; i < 64u; i++) {
    float2 a = inl[b][i];
    float2 ww = wp[(size_t)i * 64u];
    acc.x += a.x * ww.x - a.y * ww.y;
    acc.y += a.x * ww.y + a.y * ww.x;
  }
  oh[(size_t)(k * 256u + b * 64u + o) * 108u + fg] = acc;
}

// ---------------------------------------------------------------------------
// K5: fused inverse sparse DFT + synthesis (unchanged from R2, validated).
__global__ __launch_bounds__(256) void k_invsynth(const float2* __restrict__ oh,
                                                  const float* __restrict__ x,
                                                  float* __restrict__ out) {
  __shared__ float2 hh[8][108];
  __shared__ float2 gx[8][6][3];
  __shared__ float2 uu[8][3][16];
  __shared__ float W[8][16][16];
  unsigned tid = threadIdx.x;
  unsigned slab = blockIdx.x & 15u;
  unsigned bo = blockIdx.x >> 4;
  for (unsigned i = tid; i < 864u; i += 256u) {
    unsigned k = i / 108u, f = i - k * 108u;
    ((float2*)hh)[i] = oh[(size_t)((k << 8) + bo) * 108u + f];
  }
  __syncthreads();
  if (tid < 144u) {
    unsigned k = tid / 18u, r = tid - k * 18u;
    float re = 0.f, im = 0.f;
#pragma unroll
    for (int kxi = 0; kxi < 6; kxi++) {
      float2 v = hh[k][kxi * 18 + r];
      int t16 = (KYv[kxi] * (int)slab) & 15;
      float c = C16c[t16], sn = S16c[t16];
      re += v.x * c - v.y * sn;
      im += v.x * sn + v.y * c;
    }
    ((float2*)gx)[tid] = make_float2(re, im);
  }
  __syncthreads();
  for (unsigned i = tid; i < 384u; i += 256u) {
    unsigned k = i / 48u, rem = i - k * 48u;
    unsigned kz = rem >> 4, ny = rem & 15u;
    float re = 0.f, im = 0.f;
#pragma unroll
    for (int kyi = 0; kyi < 6; kyi++) {
      float2 v = gx[k][kyi][kz];
      int t16 = (KYv[kyi] * (int)ny) & 15;
      float c = C16c[t16], sn = S16c[t16];
      re += v.x * c - v.y * sn;
      im += v.x * sn + v.y * c;
    }
    uu[k][kz][ny] = make_float2(re, im);
  }
  __syncthreads();
  {
    unsigned ny = tid >> 4, nz = tid & 15u;
    float c1 = C16c[nz], s1 = S16c[nz];
    int t2 = (2 * nz) & 15;
    float c2 = C16c[t2], s2 = S16c[t2];
    float val[8];
#pragma unroll
    for (int k = 0; k < 8; k++) {
      float2 u0 = uu[k][0][ny], u1 = uu[k][1][ny], u2 = uu[k][2][ny];
      val[k] = (u0.x + 2.f * (u1.x * c1 - u1.y * s1) + 2.f * (u2.x * c2 - u2.y * s2)) * (1.f / 4096.f);
    }
#pragma unroll
    for (int st = 1; st < 8; st <<= 1)
#pragma unroll
      for (int i2 = 0; i2 < 8; i2++)
        if (!(i2 & st)) {
          float a = val[i2], b = val[i2 | st];
          val[i2] = a + b;
          val[i2 | st] = a - b;
        }
#pragma unroll
    for (int m = 0; m < 8; m++) W[m][ny][nz] = val[m];
  }
  __syncthreads();
  unsigned z4 = tid & 15u;
  unsigned y0 = (tid >> 4) & 1u;
  unsigned x0 = (tid >> 5) & 1u;
  unsigned w = tid >> 6;
  const float* xp = x + ((size_t)bo << 18);
  float* op = out + ((size_t)bo << 18);
#pragma unroll 4
  for (unsigned it = 0; it < 16u; ++it) {
    unsigned idx = w + (it << 2);
    unsigned lx1 = idx & 1u;
    unsigned yh = idx >> 1;
    unsigned X = (slab << 2) + (lx1 << 1) + x0;
    unsigned Y = (yh << 1) + y0;
    size_t off = ((((size_t)X << 6) + Y) << 6) + (z4 << 2);
    float4 v = *(const float4*)(xp + off);
    float h0 = v.x + v.y, h1 = v.z + v.w;
    h0 += __shfl_xor(h0, 16);
    h1 += __shfl_xor(h1, 16);
    h0 += __shfl_xor(h0, 32);
    h1 += __shfl_xor(h1, 32);
    float m0 = h0 * 0.125f;
    float m1 = h1 * 0.125f;
    unsigned ny = yh >> 1, nz = z4;
    unsigned mm = (lx1 << 2) | ((yh & 1u) << 1);
    float c0 = 0.125f * W[mm][ny][nz] - m0;
    float c1 = 0.125f * W[mm | 1u][ny][nz] - m1;
    v.x += c0;
    v.y += c0;
    v.z += c1;
    v.w += c1;
    *(float4*)(op + off) = v;
  }
}

extern "C" void kernel_launch(void* const* d_in, const int* in_sizes, int n_in,
                              void* d_out, int out_size, void* d_ws, size_t ws_size,
                              hipStream_t stream) {
  const float* x = (const float*)d_in[0];
  const float* w = (const float*)d_in[1];
  float* out = (float*)d_out;

  const size_t G_F2 = 4096ull * 144;        // 589,824 f2 (4.72 MB)
  const size_t HAT_F2 = 2048ull * 108;      // 221,184 f2 (1.77 MB)
  const size_t WT_F2 = 32ull * 27 * 4096;   // 3,538,944 f2 (28.3 MB)
  const size_t G_B = G_F2 * 8, HAT_B = HAT_F2 * 8, WT_B = WT_F2 * 8;

  float2 *g, *ih, *wt, *oh;
  char* ws = (char*)d_ws;
  if (ws_size >= G_B + 2 * HAT_B + WT_B) {
    g = (float2*)ws;
    ih = (float2*)(ws + G_B);
    wt = (float2*)(ws + G_B + HAT_B);
    oh = (float2*)(ws + G_B + HAT_B + WT_B);
  } else {
    // d_out doubles as dead scratch (fully overwritten by k_invsynth, which
    // reads only x and oh). oh must survive into k_invsynth -> keep in ws.
    g = (float2*)d_out;
    ih = (float2*)((char*)d_out + G_B);
    wt = (float2*)((char*)d_out + G_B + HAT_B);
    oh = (float2*)ws;  // needs 1.77 MB
  }

  k_front<<<4096, 256, 0, stream>>>(x, g);
  k_xdft<<<2048, 128, 0, stream>>>(g, ih);
  k_wtr<<<512, 256, 0, stream>>>((const float2*)w, wt);
  k_mix2<<<864, 256, 0, stream>>>(wt, ih, oh);
  k_invsynth<<<4096, 256, 0, stream>>>(oh, x, out);
}

// Round 4
// 193.698 us; speedup vs baseline: 1.1701x; 1.0708x over previous
//
#include <hip/hip_runtime.h>

// WaveConv3d: 2-level 3D Haar DWT + low-freq spectral conv on the 8 level-2
// subbands + inverse DWT, algebraically reduced to:
//   s_k    = signed 4x4x4 block-reduce of x           (8 subbands, 16^3)
//   ih     = sparse 3D DFT of s_k (6x6x3 freqs)
//   oh     = per-frequency 64->64 channel mix
//   out    = x - mean_{2x2x2}(x) + (1/8) sum_k sign_k(cell) * idft(oh_k)
// 3 kernels: K1 = [analyze+z/y-DFT] ++ [weight transpose] (independent halves
// in one grid), K2 = x-DFT + mix, K3 = inverse DFT + synthesis.

__constant__ float C16c[16] = {
  1.0f, 0.92387953251128675f, 0.70710678118654752f, 0.38268343236508977f,
  0.0f, -0.38268343236508977f, -0.70710678118654752f, -0.92387953251128675f,
  -1.0f, -0.92387953251128675f, -0.70710678118654752f, -0.38268343236508977f,
  0.0f, 0.38268343236508977f, 0.70710678118654752f, 0.92387953251128675f
};
__constant__ float S16c[16] = {
  0.0f, 0.38268343236508977f, 0.70710678118654752f, 0.92387953251128675f,
  1.0f, 0.92387953251128675f, 0.70710678118654752f, 0.38268343236508977f,
  0.0f, -0.38268343236508977f, -0.70710678118654752f, -0.92387953251128675f,
  -1.0f, -0.92387953251128675f, -0.70710678118654752f, -0.38268343236508977f
};
__constant__ int KYv[6] = {0, 1, 2, 13, 14, 15};

// ---------------------------------------------------------------------------
// K1: blocks [0,4096): fused analyze + z-DFT + y-DFT -> g2[row][bc*16+px],
//     row = k*18 + kyi*3 + kz. Fully-coalesced 1KB-per-wave-instr loads.
//     blocks [4096,6144): weight transpose w[kc][i][o][f] -> wt[kc][f][i][o].
__global__ __launch_bounds__(256) void k1_front_wtr(const float* __restrict__ x,
                                                    const float2* __restrict__ w2,
                                                    float2* __restrict__ g2,
                                                    float2* __restrict__ wt) {
  __shared__ __align__(16) unsigned char smem[13824];
  unsigned tid = threadIdx.x;
  if (blockIdx.x < 4096u) {
    float* sm = (float*)smem;                 // [8][16][17] floats (8704 B)
    float2* fz = (float2*)(smem + 8704);      // [8][3][17] f2    (3264 B)
    unsigned px = blockIdx.x & 15u;
    unsigned bc = blockIdx.x >> 4;
    const float4* xp4 = (const float4*)(x + ((size_t)bc << 18)) + (size_t)px * 4096u;
    unsigned z4 = tid & 15u;
#pragma unroll
    for (int q = 0; q < 4; q++) {
      float a00 = 0.f, a01 = 0.f, a10 = 0.f, a11 = 0.f;  // [dx][zhalf]
#pragma unroll
      for (int i = 0; i < 4; i++) {
        float4 v = xp4[i * 1024 + q * 256 + tid];
        float h0 = v.x + v.y, h1 = v.z + v.w;
        a00 += h0; a01 += h1;
        if (i < 2) { a10 += h0; a11 += h1; } else { a10 -= h0; a11 -= h1; }
      }
      // y-pair sums (stage 1)
      float p00 = a00 + __shfl_xor(a00, 16);
      float p01 = a01 + __shfl_xor(a01, 16);
      float p10 = a10 + __shfl_xor(a10, 16);
      float p11 = a11 + __shfl_xor(a11, 16);
      // stage 2: sum + signed diff over pair-of-pairs
      float q00 = __shfl_xor(p00, 32), q01 = __shfl_xor(p01, 32);
      float q10 = __shfl_xor(p10, 32), q11 = __shfl_xor(p11, 32);
      bool hi = (tid >> 5) & 1u;  // (Y>>1)&1
      float ya0 = p00 + q00, yd0 = hi ? (q00 - p00) : (p00 - q00);
      float ya1 = p01 + q01, yd1 = hi ? (q01 - p01) : (p01 - q01);
      float za0 = p10 + q10, zd0 = hi ? (q10 - p10) : (p10 - q10);
      float za1 = p11 + q11, zd1 = hi ? (q11 - p11) : (p11 - q11);
      if (((tid >> 4) & 3u) == 0u) {
        unsigned py = q * 4 + (tid >> 6);
        float* smp = sm + py * 17u + z4;
        // k = dx*4+dy*2+dz ; values: [dx][dy] = {(ya,yd) x (a00-line, a10-line)}
        smp[0 * 272] = (ya0 + ya1) * 0.125f;   // 000
        smp[1 * 272] = (ya0 - ya1) * 0.125f;   // 001
        smp[2 * 272] = (yd0 + yd1) * 0.125f;   // 010
        smp[3 * 272] = (yd0 - yd1) * 0.125f;   // 011
        smp[4 * 272] = (za0 + za1) * 0.125f;   // 100
        smp[5 * 272] = (za0 - za1) * 0.125f;   // 101
        smp[6 * 272] = (zd0 + zd1) * 0.125f;   // 110
        smp[7 * 272] = (zd0 - zd1) * 0.125f;   // 111
      }
    }
    __syncthreads();
    if (tid < 128u) {  // z-DFT: thread = (k, ny), 3 kz outputs
      unsigned k = tid >> 4, y = tid & 15u;
      const float* row = sm + k * 272u + y * 17u;
#pragma unroll
      for (int kz = 0; kz < 3; kz++) {
        float re = 0.f, im = 0.f;
#pragma unroll
        for (int nz = 0; nz < 16; nz++) {
          float vv = row[nz];
          int t16 = (kz * nz) & 15;
          re += vv * C16c[t16];
          im -= vv * S16c[t16];
        }
        fz[k * 51u + kz * 17u + y] = make_float2(re, im);
      }
    }
    __syncthreads();
    if (tid < 144u) {  // y-DFT: thread = row = k*18 + kyi*3 + kz
      unsigned k = tid / 18u, r = tid - k * 18u;
      unsigned kyi = r / 3u, kz = r - kyi * 3u;
      int ky = KYv[kyi];
      float re = 0.f, im = 0.f;
#pragma unroll
      for (int ny = 0; ny < 16; ny++) {
        float2 vv = fz[k * 51u + kz * 17u + ny];
        int t16 = (ky * ny) & 15;
        float c = C16c[t16], sn = S16c[t16];
        re += vv.x * c + vv.y * sn;
        im += vv.y * c - vv.x * sn;
      }
      g2[(size_t)tid * 4096u + blockIdx.x] = make_float2(re, im);
    }
  } else {
    // weight transpose: wb = (kc, i)
    float4* lw4 = (float4*)smem;
    float2* lw2 = (float2*)smem;
    unsigned wb = blockIdx.x - 4096u;
    unsigned kc = wb >> 6, i = wb & 63u;
    const float4* src = (const float4*)(w2 + ((size_t)kc * 64u + i) * 1728u);
    for (unsigned t = tid; t < 864u; t += 256u) lw4[t] = src[t];
    __syncthreads();
    float2* dst = wt + (size_t)kc * 110592u + (size_t)i * 64u;
    for (unsigned t = tid; t < 1728u; t += 256u) {
      unsigned f = t >> 6, o = t & 63u;
      dst[(size_t)f * 4096u + o] = lw2[o * 27u + f];
    }
  }
}

// ---------------------------------------------------------------------------
// K2: x-DFT + per-frequency channel mix. WG = (kc, f); 256 thr.
// Phase A: thread bc computes ih[bc] by 16-pt x-DFT from g2 row (registers).
// Phase B: thread (b,o) mixes over i with coalesced wt stream (read once).
__global__ __launch_bounds__(256) void k2_mix(const float2* __restrict__ wt,
                                              const float2* __restrict__ g2,
                                              float2* __restrict__ oh2) {
  __shared__ float2 inl[256];
  unsigned tid = threadIdx.x;
  unsigned f = blockIdx.x % 27u;
  unsigned kc = blockIdx.x / 27u;
  unsigned k = kc >> 2, corner = kc & 3u;
  unsigned kz = f % 3u, kyl = (f / 3u) % 3u, kxl = f / 9u;
  unsigned kxi = kxl + 3u * (corner & 1u);
  unsigned kyi = kyl + 3u * (corner >> 1);
  unsigned fg = kxi * 18u + kyi * 3u + kz;
  unsigned row = k * 18u + kyi * 3u + kz;
  {  // Phase A: x-DFT for bc = tid
    const float2* gp = g2 + (size_t)row * 4096u + tid * 16u;
    int kx = KYv[kxi];
    float re = 0.f, im = 0.f;
#pragma unroll
    for (int nx = 0; nx < 16; nx++) {
      float2 vv = gp[nx];
      int t16 = (kx * nx) & 15;
      float c = C16c[t16], sn = S16c[t16];
      re += vv.x * c + vv.y * sn;
      im += vv.y * c - vv.x * sn;
    }
    inl[tid] = make_float2(re, im);
  }
  __syncthreads();
  unsigned b = tid >> 6, o = tid & 63u;
  const float2* wp = wt + ((size_t)kc * 27u + f) * 4096u + o;
  float2 acc = make_float2(0.f, 0.f);
#pragma unroll 8
  for (unsigned i = 0; i < 64u; i++) {
    float2 a = inl[(b << 6) | i];
    float2 ww = wp[(size_t)i * 64u];
    acc.x += a.x * ww.x - a.y * ww.y;
    acc.y += a.x * ww.y + a.y * ww.x;
  }
  oh2[((size_t)(b * 64u + o)) * 864u + k * 108u + fg] = acc;
}

// ---------------------------------------------------------------------------
// K3: fused inverse sparse DFT + synthesis. WG = (bo, slab=nx).
// Streaming phase: x-pair in registers, y-pair via shfl, 1KB/wave-instr.
__global__ __launch_bounds__(256) void k3_invsynth(const float2* __restrict__ oh2,
                                                   const float* __restrict__ x,
                                                   float* __restrict__ out) {
  __shared__ float2 hh[8][108];
  __shared__ float2 gx[8][6][3];
  __shared__ float2 uu[8][3][16];
  __shared__ float W[8][16][16];
  unsigned tid = threadIdx.x;
  unsigned slab = blockIdx.x & 15u;
  unsigned bo = blockIdx.x >> 4;
  for (unsigned i = tid; i < 864u; i += 256u)
    ((float2*)hh)[i] = oh2[(size_t)bo * 864u + i];
  __syncthreads();
  if (tid < 144u) {  // x-inverse at nx = slab
    unsigned k = tid / 18u, r = tid - k * 18u;
    float re = 0.f, im = 0.f;
#pragma unroll
    for (int kxi = 0; kxi < 6; kxi++) {
      float2 v = hh[k][kxi * 18 + r];
      int t16 = (KYv[kxi] * (int)slab) & 15;
      float c = C16c[t16], sn = S16c[t16];
      re += v.x * c - v.y * sn;
      im += v.x * sn + v.y * c;
    }
    ((float2*)gx)[tid] = make_float2(re, im);
  }
  __syncthreads();
  for (unsigned i = tid; i < 384u; i += 256u) {  // y-inverse
    unsigned k = i / 48u, rem = i - k * 48u;
    unsigned kz = rem >> 4, ny = rem & 15u;
    float re = 0.f, im = 0.f;
#pragma unroll
    for (int kyi = 0; kyi < 6; kyi++) {
      float2 v = gx[k][kyi][kz];
      int t16 = (KYv[kyi] * (int)ny) & 15;
      float c = C16c[t16], sn = S16c[t16];
      re += v.x * c - v.y * sn;
      im += v.x * sn + v.y * c;
    }
    uu[k][kz][ny] = make_float2(re, im);
  }
  __syncthreads();
  {  // z-inverse + signed Hadamard over k
    unsigned ny = tid >> 4, nz = tid & 15u;
    float c1 = C16c[nz], s1 = S16c[nz];
    int t2 = (2 * nz) & 15;
    float c2 = C16c[t2], s2 = S16c[t2];
    float val[8];
#pragma unroll
    for (int k = 0; k < 8; k++) {
      float2 u0 = uu[k][0][ny], u1 = uu[k][1][ny], u2 = uu[k][2][ny];
      val[k] = (u0.x + 2.f * (u1.x * c1 - u1.y * s1) + 2.f * (u2.x * c2 - u2.y * s2)) * (1.f / 4096.f);
    }
#pragma unroll
    for (int st = 1; st < 8; st <<= 1)
#pragma unroll
      for (int i2 = 0; i2 < 8; i2++)
        if (!(i2 & st)) {
          float a = val[i2], b = val[i2 | st];
          val[i2] = a + b;
          val[i2 | st] = a - b;
        }
#pragma unroll
    for (int m = 0; m < 8; m++) W[m][ny][nz] = val[m];
  }
  __syncthreads();
  // Streaming: w = wave, l = lane; z4 = l&15, y2 = l>>4.
  unsigned w = tid >> 6, l = tid & 63u;
  unsigned z4 = l & 15u, y2 = l >> 4;
  const float* xp = x + ((size_t)bo << 18);
  float* op = out + ((size_t)bo << 18);
  unsigned mmy = ((y2 >> 1) & 1u) << 1;
  unsigned nz = z4;
#pragma unroll
  for (unsigned r2 = 0; r2 < 8u; ++r2) {
    unsigned xp2 = r2 & 1u, yg = r2 >> 1;
    unsigned X0 = (slab << 2) + (xp2 << 1);
    unsigned Y = (yg << 4) + (w << 2) + y2;
    size_t off = ((size_t)X0 << 12) + (Y << 6) + (z4 << 2);
    float4 v0 = *(const float4*)(xp + off);
    float4 v1 = *(const float4*)(xp + off + 4096u);
    float h0 = v0.x + v0.y + v1.x + v1.y;
    float h1 = v0.z + v0.w + v1.z + v1.w;
    float m0 = (h0 + __shfl_xor(h0, 16)) * 0.125f;
    float m1 = (h1 + __shfl_xor(h1, 16)) * 0.125f;
    unsigned ny = (yg << 2) + w;
    unsigned mm = (xp2 << 2) | mmy;
    float c0 = 0.125f * W[mm][ny][nz] - m0;
    float c1 = 0.125f * W[mm | 1u][ny][nz] - m1;
    v0.x += c0; v0.y += c0; v0.z += c1; v0.w += c1;
    v1.x += c0; v1.y += c0; v1.z += c1; v1.w += c1;
    *(float4*)(op + off) = v0;
    *(float4*)(op + off + 4096u) = v1;
  }
}

extern "C" void kernel_launch(void* const* d_in, const int* in_sizes, int n_in,
                              void* d_out, int out_size, void* d_ws, size_t ws_size,
                              hipStream_t stream) {
  const float* x = (const float*)d_in[0];
  const float* w = (const float*)d_in[1];
  float* out = (float*)d_out;

  const size_t G_F2 = 144ull * 4096;        // 589,824 f2 (4.72 MB)
  const size_t WT_F2 = 32ull * 27 * 4096;   // 3,538,944 f2 (28.3 MB)
  const size_t OH_F2 = 256ull * 864;        // 221,184 f2 (1.77 MB)
  const size_t G_B = G_F2 * 8, WT_B = WT_F2 * 8, OH_B = OH_F2 * 8;

  float2 *g2, *wt, *oh2;
  char* ws = (char*)d_ws;
  if (ws_size >= G_B + WT_B + OH_B) {
    g2 = (float2*)ws;
    wt = (float2*)(ws + G_B);
    oh2 = (float2*)(ws + G_B + WT_B);
  } else {
    // d_out doubles as dead scratch for g2/wt (consumed before K3 overwrites
    // d_out). oh2 must survive into K3 -> keep in ws (needs 1.77 MB).
    g2 = (float2*)d_out;
    wt = (float2*)((char*)d_out + G_B);
    oh2 = (float2*)ws;
  }

  k1_front_wtr<<<6144, 256, 0, stream>>>(x, (const float2*)w, g2, wt);
  k2_mix<<<864, 256, 0, stream>>>(wt, g2, oh2);
  k3_invsynth<<<4096, 256, 0, stream>>>(oh2, x, out);
}

// Round 6
// 167.452 us; speedup vs baseline: 1.3535x; 1.1567x over previous
//
#include <hip/hip_runtime.h>

// WaveConv3d: 2-level 3D Haar DWT + low-freq spectral conv on the 8 level-2
// subbands + inverse DWT, algebraically reduced to:
//   s_k    = signed 4x4x4 block-reduce of x           (8 subbands, 16^3)
//   ih     = sparse 3D DFT of s_k (6x6x3 freqs)
//   oh     = per-frequency 64->64 channel mix
//   out    = x - mean_{2x2x2}(x) + (1/8) sum_k sign_k(cell) * idft(oh_k)
// K1 = [analyze+z/y-DFT] ++ [weight transpose], K2 = x-DFT + mix,
// K3 = inverse DFT + synthesis (NT x-load / NT out-store, reverse order so
// K3 re-reads x in LLC-hot order behind K1).

typedef float f32x4 __attribute__((ext_vector_type(4)));
typedef float f32x2 __attribute__((ext_vector_type(2)));

__constant__ float C16c[16] = {
  1.0f, 0.92387953251128675f, 0.70710678118654752f, 0.38268343236508977f,
  0.0f, -0.38268343236508977f, -0.70710678118654752f, -0.92387953251128675f,
  -1.0f, -0.92387953251128675f, -0.70710678118654752f, -0.38268343236508977f,
  0.0f, 0.38268343236508977f, 0.70710678118654752f, 0.92387953251128675f
};
__constant__ float S16c[16] = {
  0.0f, 0.38268343236508977f, 0.70710678118654752f, 0.92387953251128675f,
  1.0f, 0.92387953251128675f, 0.70710678118654752f, 0.38268343236508977f,
  0.0f, -0.38268343236508977f, -0.70710678118654752f, -0.92387953251128675f,
  -1.0f, -0.92387953251128675f, -0.70710678118654752f, -0.38268343236508977f
};
__constant__ int KYv[6] = {0, 1, 2, 13, 14, 15};

// ---------------------------------------------------------------------------
// K1: blocks [0,4096): fused analyze + z-DFT + y-DFT.
//     g2 layout: [row][px][bc], row = k*18 + kyi*3 + kz  (4.7 MB).
//     blocks [4096,6144): weight transpose w[kc][i][o][f] -> wt[kc][f][i][o].
__global__ __launch_bounds__(256) void k1_front_wtr(const float* __restrict__ x,
                                                    const float2* __restrict__ w2,
                                                    float2* __restrict__ g2,
                                                    float2* __restrict__ wt) {
  __shared__ __align__(16) unsigned char smem[13824];
  unsigned tid = threadIdx.x;
  if (blockIdx.x < 4096u) {
    float* sm = (float*)smem;                 // [8][16][17] floats (8704 B)
    float2* fz = (float2*)(smem + 8704);      // [8][3][17] f2    (3264 B)
    unsigned px = blockIdx.x & 15u;
    unsigned bc = blockIdx.x >> 4;
    const f32x4* xp4 = (const f32x4*)(x + ((size_t)bc << 18)) + (size_t)px * 4096u;
    unsigned z4 = tid & 15u;
#pragma unroll
    for (int q = 0; q < 4; q++) {
      float a00 = 0.f, a01 = 0.f, a10 = 0.f, a11 = 0.f;  // [dx][zhalf]
#pragma unroll
      for (int i = 0; i < 4; i++) {
        f32x4 v = xp4[i * 1024 + q * 256 + tid];
        float h0 = v.x + v.y, h1 = v.z + v.w;
        a00 += h0; a01 += h1;
        if (i < 2) { a10 += h0; a11 += h1; } else { a10 -= h0; a11 -= h1; }
      }
      float p00 = a00 + __shfl_xor(a00, 16);
      float p01 = a01 + __shfl_xor(a01, 16);
      float p10 = a10 + __shfl_xor(a10, 16);
      float p11 = a11 + __shfl_xor(a11, 16);
      float q00 = __shfl_xor(p00, 32), q01 = __shfl_xor(p01, 32);
      float q10 = __shfl_xor(p10, 32), q11 = __shfl_xor(p11, 32);
      bool hi = (tid >> 5) & 1u;
      float ya0 = p00 + q00, yd0 = hi ? (q00 - p00) : (p00 - q00);
      float ya1 = p01 + q01, yd1 = hi ? (q01 - p01) : (p01 - q01);
      float za0 = p10 + q10, zd0 = hi ? (q10 - p10) : (p10 - q10);
      float za1 = p11 + q11, zd1 = hi ? (q11 - p11) : (p11 - q11);
      if (((tid >> 4) & 3u) == 0u) {
        unsigned py = q * 4 + (tid >> 6);
        float* smp = sm + py * 17u + z4;
        smp[0 * 272] = (ya0 + ya1) * 0.125f;   // k=000
        smp[1 * 272] = (ya0 - ya1) * 0.125f;   // 001
        smp[2 * 272] = (yd0 + yd1) * 0.125f;   // 010
        smp[3 * 272] = (yd0 - yd1) * 0.125f;   // 011
        smp[4 * 272] = (za0 + za1) * 0.125f;   // 100
        smp[5 * 272] = (za0 - za1) * 0.125f;   // 101
        smp[6 * 272] = (zd0 + zd1) * 0.125f;   // 110
        smp[7 * 272] = (zd0 - zd1) * 0.125f;   // 111
      }
    }
    __syncthreads();
    if (tid < 128u) {  // z-DFT
      unsigned k = tid >> 4, y = tid & 15u;
      const float* row = sm + k * 272u + y * 17u;
#pragma unroll
      for (int kz = 0; kz < 3; kz++) {
        float re = 0.f, im = 0.f;
#pragma unroll
        for (int nz = 0; nz < 16; nz++) {
          float vv = row[nz];
          int t16 = (kz * nz) & 15;
          re += vv * C16c[t16];
          im -= vv * S16c[t16];
        }
        fz[k * 51u + kz * 17u + y] = make_float2(re, im);
      }
    }
    __syncthreads();
    if (tid < 144u) {  // y-DFT -> g2[row][px][bc]
      unsigned k = tid / 18u, r = tid - k * 18u;
      unsigned kyi = r / 3u, kz = r - kyi * 3u;
      int ky = KYv[kyi];
      float re = 0.f, im = 0.f;
#pragma unroll
      for (int ny = 0; ny < 16; ny++) {
        float2 vv = fz[k * 51u + kz * 17u + ny];
        int t16 = (ky * ny) & 15;
        float c = C16c[t16], sn = S16c[t16];
        re += vv.x * c + vv.y * sn;
        im += vv.y * c - vv.x * sn;
      }
      g2[((size_t)tid * 16u + px) * 256u + bc] = make_float2(re, im);
    }
  } else {
    // weight transpose: wb = (kc, i)
    f32x4* lw4 = (f32x4*)smem;
    float2* lw2 = (float2*)smem;
    unsigned wb = blockIdx.x - 4096u;
    unsigned kc = wb >> 6, i = wb & 63u;
    const f32x4* src = (const f32x4*)(w2 + ((size_t)kc * 64u + i) * 1728u);
    for (unsigned t = tid; t < 864u; t += 256u) lw4[t] = src[t];
    __syncthreads();
    float2* dst = wt + (size_t)kc * 110592u + (size_t)i * 64u;
    for (unsigned t = tid; t < 1728u; t += 256u) {
      unsigned f = t >> 6, o = t & 63u;
      dst[(size_t)f * 4096u + o] = lw2[o * 27u + f];
    }
  }
}

// ---------------------------------------------------------------------------
// K2: x-DFT + per-frequency channel mix. WG = (kc, f); 256 thr.
__global__ __launch_bounds__(256) void k2_mix(const float2* __restrict__ wt,
                                              const float2* __restrict__ g2,
                                              float2* __restrict__ oh2) {
  __shared__ float2 inl[256];
  unsigned tid = threadIdx.x;
  unsigned f = blockIdx.x % 27u;
  unsigned kc = blockIdx.x / 27u;
  unsigned k = kc >> 2, corner = kc & 3u;
  unsigned kz = f % 3u, kyl = (f / 3u) % 3u, kxl = f / 9u;
  unsigned kxi = kxl + 3u * (corner & 1u);
  unsigned kyi = kyl + 3u * (corner >> 1);
  unsigned fg = kxi * 18u + kyi * 3u + kz;
  unsigned row = k * 18u + kyi * 3u + kz;
  {  // Phase A: x-DFT for bc = tid; g2 read coalesced (2KB/wave-instr)
    const float2* gp = g2 + (size_t)row * 4096u + tid;
    int kx = KYv[kxi];
    float re = 0.f, im = 0.f;
#pragma unroll
    for (int nx = 0; nx < 16; nx++) {
      float2 vv = gp[nx * 256];
      int t16 = (kx * nx) & 15;
      float c = C16c[t16], sn = S16c[t16];
      re += vv.x * c + vv.y * sn;
      im += vv.y * c - vv.x * sn;
    }
    inl[tid] = make_float2(re, im);
  }
  __syncthreads();
  unsigned b = tid >> 6, o = tid & 63u;
  const f32x2* wp = (const f32x2*)(wt + ((size_t)kc * 27u + f) * 4096u + o);
  float2 acc = make_float2(0.f, 0.f);
#pragma unroll 16
  for (unsigned i = 0; i < 64u; i++) {
    float2 a = inl[(b << 6) | i];
    f32x2 ww = __builtin_nontemporal_load(wp + (size_t)i * 64u);
    acc.x += a.x * ww.x - a.y * ww.y;
    acc.y += a.x * ww.y + a.y * ww.x;
  }
  oh2[((size_t)(b * 64u + o)) * 864u + k * 108u + fg] = acc;
}

// ---------------------------------------------------------------------------
// K3: fused inverse sparse DFT + synthesis. WG = (bo reversed, slab-pair).
// NT x-loads + NT out-stores keep LLC holding x (written there by K1).
__global__ __launch_bounds__(256) void k3_invsynth(const float2* __restrict__ oh2,
                                                   const float* __restrict__ x,
                                                   float* __restrict__ out) {
  __shared__ float2 hh[864];          // [k][fg]
  __shared__ float2 gx[2][8][18];     // [sl][k][kyi*3+kz]
  __shared__ float2 uu[2][8][3][16];  // [sl][k][kz][ny]
  __shared__ float W[2][8][16][16];   // [sl][m][ny][nz]
  unsigned tid = threadIdx.x;
  unsigned sp = blockIdx.x & 7u;              // slab pair: nx = sp*2 + sl
  unsigned bo = 255u - (blockIdx.x >> 3);     // reversed for LLC locality
  for (unsigned i = tid; i < 864u; i += 256u)
    hh[i] = oh2[(size_t)bo * 864u + i];
  __syncthreads();
  for (unsigned i = tid; i < 288u; i += 256u) {  // x-inverse (both slabs)
    unsigned sl = i / 144u, j = i - sl * 144u;
    unsigned k = j / 18u, r = j - k * 18u;
    unsigned nx = sp * 2u + sl;
    float re = 0.f, im = 0.f;
#pragma unroll
    for (int kxi = 0; kxi < 6; kxi++) {
      float2 v = hh[k * 108u + kxi * 18 + r];
      int t16 = (KYv[kxi] * (int)nx) & 15;
      float c = C16c[t16], sn = S16c[t16];
      re += v.x * c - v.y * sn;
      im += v.x * sn + v.y * c;
    }
    gx[sl][k][r] = make_float2(re, im);
  }
  __syncthreads();
  for (unsigned i = tid; i < 768u; i += 256u) {  // y-inverse
    unsigned sl = i / 384u, j = i - sl * 384u;
    unsigned k = j / 48u, rem = j - k * 48u;
    unsigned kz = rem >> 4, ny = rem & 15u;
    float re = 0.f, im = 0.f;
#pragma unroll
    for (int kyi = 0; kyi < 6; kyi++) {
      float2 v = gx[sl][k][kyi * 3 + kz];
      int t16 = (KYv[kyi] * (int)ny) & 15;
      float c = C16c[t16], sn = S16c[t16];
      re += v.x * c - v.y * sn;
      im += v.x * sn + v.y * c;
    }
    uu[sl][k][kz][ny] = make_float2(re, im);
  }
  __syncthreads();
  for (unsigned i = tid; i < 512u; i += 256u) {  // z-inverse + Hadamard
    unsigned sl = i >> 8, ny = (i >> 4) & 15u, nz = i & 15u;
    float c1 = C16c[nz], s1 = S16c[nz];
    int t2 = (2 * nz) & 15;
    float c2 = C16c[t2], s2 = S16c[t2];
    float val[8];
#pragma unroll
    for (int k = 0; k < 8; k++) {
      float2 u0 = uu[sl][k][0][ny], u1 = uu[sl][k][1][ny], u2 = uu[sl][k][2][ny];
      val[k] = (u0.x + 2.f * (u1.x * c1 - u1.y * s1) + 2.f * (u2.x * c2 - u2.y * s2)) * (1.f / 4096.f);
    }
#pragma unroll
    for (int st = 1; st < 8; st <<= 1)
#pragma unroll
      for (int i2 = 0; i2 < 8; i2++)
        if (!(i2 & st)) {
          float a = val[i2], b = val[i2 | st];
          val[i2] = a + b;
          val[i2 | st] = a - b;
        }
#pragma unroll
    for (int m = 0; m < 8; m++) W[sl][m][ny][nz] = val[m];
  }
  __syncthreads();
  unsigned w = tid >> 6, l = tid & 63u;
  unsigned z4 = l & 15u, y2 = l >> 4;
  unsigned mmy = ((y2 >> 1) & 1u) << 1;
  const float* xp = x + ((size_t)bo << 18);
  float* op = out + ((size_t)bo << 18);
#pragma unroll
  for (unsigned sl = 0; sl < 2u; ++sl) {
#pragma unroll
    for (unsigned r2 = 0; r2 < 8u; ++r2) {
      unsigned xp2 = r2 & 1u, yg = r2 >> 1;
      unsigned X0 = ((sp * 2u + sl) << 2) + (xp2 << 1);
      unsigned Y = (yg << 4) + (w << 2) + y2;
      size_t off = ((size_t)X0 << 12) + (Y << 6) + (z4 << 2);
      f32x4 v0 = __builtin_nontemporal_load((const f32x4*)(xp + off));
      f32x4 v1 = __builtin_nontemporal_load((const f32x4*)(xp + off + 4096u));
      float h0 = v0.x + v0.y + v1.x + v1.y;
      float h1 = v0.z + v0.w + v1.z + v1.w;
      float m0 = (h0 + __shfl_xor(h0, 16)) * 0.125f;
      float m1 = (h1 + __shfl_xor(h1, 16)) * 0.125f;
      unsigned ny = (yg << 2) + w;
      unsigned mm = (xp2 << 2) | mmy;
      float c0 = 0.125f * W[sl][mm][ny][z4] - m0;
      float c1 = 0.125f * W[sl][mm | 1u][ny][z4] - m1;
      v0.x += c0; v0.y += c0; v0.z += c1; v0.w += c1;
      v1.x += c0; v1.y += c0; v1.z += c1; v1.w += c1;
      __builtin_nontemporal_store(v0, (f32x4*)(op + off));
      __builtin_nontemporal_store(v1, (f32x4*)(op + off + 4096u));
    }
  }
}

extern "C" void kernel_launch(void* const* d_in, const int* in_sizes, int n_in,
                              void* d_out, int out_size, void* d_ws, size_t ws_size,
                              hipStream_t stream) {
  const float* x = (const float*)d_in[0];
  const float* w = (const float*)d_in[1];
  float* out = (float*)d_out;

  const size_t G_F2 = 144ull * 4096;        // 4.72 MB
  const size_t WT_F2 = 32ull * 27 * 4096;   // 28.3 MB
  const size_t OH_F2 = 256ull * 864;        // 1.77 MB
  const size_t G_B = G_F2 * 8, WT_B = WT_F2 * 8, OH_B = OH_F2 * 8;

  float2 *g2, *wt, *oh2;
  char* ws = (char*)d_ws;
  if (ws_size >= G_B + WT_B + OH_B) {
    g2 = (float2*)ws;
    wt = (float2*)(ws + G_B);
    oh2 = (float2*)(ws + G_B + WT_B);
  } else {
    // d_out doubles as dead scratch for g2/wt (consumed before K3 overwrites
    // d_out). oh2 must survive into K3 -> keep in ws (needs 1.77 MB).
    g2 = (float2*)d_out;
    wt = (float2*)((char*)d_out + G_B);
    oh2 = (float2*)ws;
  }

  k1_front_wtr<<<6144, 256, 0, stream>>>(x, (const float2*)w, g2, wt);
  k2_mix<<<864, 256, 0, stream>>>(wt, g2, oh2);
  k3_invsynth<<<2048, 256, 0, stream>>>(oh2, x, out);
}

// Round 7
// 153.909 us; speedup vs baseline: 1.4726x; 1.0880x over previous
//
#include <hip/hip_runtime.h>

// WaveConv3d: 2-level 3D Haar DWT + low-freq spectral conv on the 8 level-2
// subbands + inverse DWT, algebraically reduced to:
//   s_k    = signed 4x4x4 block-reduce of x           (8 subbands, 16^3)
//   ih     = sparse 3D DFT of s_k (6x6x3 freqs)
//   oh     = per-frequency 64->64 channel mix
//   out    = x - mean_{2x2x2}(x) + (1/8) sum_k sign_k(cell) * idft(oh_k)
// K1 = [analyze+z/y-DFT] ++ [weight transpose->bf16], K2 = x-DFT + mix,
// K3 = inverse DFT + synthesis. LLC hygiene: x read with normal loads in both
// K1 and K3 (stays resident across graph replays); wt is bf16 + NT both ways
// (never pollutes LLC); out stores NT (bypass).

typedef float f32x4 __attribute__((ext_vector_type(4)));

__device__ __forceinline__ unsigned short f2bf(float v) {
  unsigned u = __float_as_uint(v);
  u = (u + 0x7FFFu + ((u >> 16) & 1u)) >> 16;  // RNE
  return (unsigned short)u;
}
__device__ __forceinline__ float bf2f(unsigned short b) {
  return __uint_as_float(((unsigned)b) << 16);
}

__constant__ float C16c[16] = {
  1.0f, 0.92387953251128675f, 0.70710678118654752f, 0.38268343236508977f,
  0.0f, -0.38268343236508977f, -0.70710678118654752f, -0.92387953251128675f,
  -1.0f, -0.92387953251128675f, -0.70710678118654752f, -0.38268343236508977f,
  0.0f, 0.38268343236508977f, 0.70710678118654752f, 0.92387953251128675f
};
__constant__ float S16c[16] = {
  0.0f, 0.38268343236508977f, 0.70710678118654752f, 0.92387953251128675f,
  1.0f, 0.92387953251128675f, 0.70710678118654752f, 0.38268343236508977f,
  0.0f, -0.38268343236508977f, -0.70710678118654752f, -0.92387953251128675f,
  -1.0f, -0.92387953251128675f, -0.70710678118654752f, -0.38268343236508977f
};
__constant__ int KYv[6] = {0, 1, 2, 13, 14, 15};

// ---------------------------------------------------------------------------
// K1: blocks [0,4096): fused analyze + z-DFT + y-DFT.
//     g2 layout: [row][px][bc], row = k*18 + kyi*3 + kz  (4.7 MB).
//     blocks [4096,6144): weight transpose -> wt_u32[kc][f][i][o] (bf16 pair).
__global__ __launch_bounds__(256) void k1_front_wtr(const float* __restrict__ x,
                                                    const float2* __restrict__ w2,
                                                    float2* __restrict__ g2,
                                                    unsigned* __restrict__ wtu) {
  __shared__ __align__(16) unsigned char smem[13824];
  unsigned tid = threadIdx.x;
  if (blockIdx.x < 4096u) {
    float* sm = (float*)smem;                 // [8][16][17] floats (8704 B)
    float2* fz = (float2*)(smem + 8704);      // [8][3][17] f2    (3264 B)
    unsigned px = blockIdx.x & 15u;
    unsigned bc = blockIdx.x >> 4;
    const f32x4* xp4 = (const f32x4*)(x + ((size_t)bc << 18)) + (size_t)px * 4096u;
    unsigned z4 = tid & 15u;
#pragma unroll
    for (int q = 0; q < 4; q++) {
      float a00 = 0.f, a01 = 0.f, a10 = 0.f, a11 = 0.f;  // [dx][zhalf]
#pragma unroll
      for (int i = 0; i < 4; i++) {
        f32x4 v = xp4[i * 1024 + q * 256 + tid];
        float h0 = v.x + v.y, h1 = v.z + v.w;
        a00 += h0; a01 += h1;
        if (i < 2) { a10 += h0; a11 += h1; } else { a10 -= h0; a11 -= h1; }
      }
      float p00 = a00 + __shfl_xor(a00, 16);
      float p01 = a01 + __shfl_xor(a01, 16);
      float p10 = a10 + __shfl_xor(a10, 16);
      float p11 = a11 + __shfl_xor(a11, 16);
      float q00 = __shfl_xor(p00, 32), q01 = __shfl_xor(p01, 32);
      float q10 = __shfl_xor(p10, 32), q11 = __shfl_xor(p11, 32);
      bool hi = (tid >> 5) & 1u;
      float ya0 = p00 + q00, yd0 = hi ? (q00 - p00) : (p00 - q00);
      float ya1 = p01 + q01, yd1 = hi ? (q01 - p01) : (p01 - q01);
      float za0 = p10 + q10, zd0 = hi ? (q10 - p10) : (p10 - q10);
      float za1 = p11 + q11, zd1 = hi ? (q11 - p11) : (p11 - q11);
      if (((tid >> 4) & 3u) == 0u) {
        unsigned py = q * 4 + (tid >> 6);
        float* smp = sm + py * 17u + z4;
        smp[0 * 272] = (ya0 + ya1) * 0.125f;   // k=000
        smp[1 * 272] = (ya0 - ya1) * 0.125f;   // 001
        smp[2 * 272] = (yd0 + yd1) * 0.125f;   // 010
        smp[3 * 272] = (yd0 - yd1) * 0.125f;   // 011
        smp[4 * 272] = (za0 + za1) * 0.125f;   // 100
        smp[5 * 272] = (za0 - za1) * 0.125f;   // 101
        smp[6 * 272] = (zd0 + zd1) * 0.125f;   // 110
        smp[7 * 272] = (zd0 - zd1) * 0.125f;   // 111
      }
    }
    __syncthreads();
    if (tid < 128u) {  // z-DFT
      unsigned k = tid >> 4, y = tid & 15u;
      const float* row = sm + k * 272u + y * 17u;
#pragma unroll
      for (int kz = 0; kz < 3; kz++) {
        float re = 0.f, im = 0.f;
#pragma unroll
        for (int nz = 0; nz < 16; nz++) {
          float vv = row[nz];
          int t16 = (kz * nz) & 15;
          re += vv * C16c[t16];
          im -= vv * S16c[t16];
        }
        fz[k * 51u + kz * 17u + y] = make_float2(re, im);
      }
    }
    __syncthreads();
    if (tid < 144u) {  // y-DFT -> g2[row][px][bc]
      unsigned k = tid / 18u, r = tid - k * 18u;
      unsigned kyi = r / 3u, kz = r - kyi * 3u;
      int ky = KYv[kyi];
      float re = 0.f, im = 0.f;
#pragma unroll
      for (int ny = 0; ny < 16; ny++) {
        float2 vv = fz[k * 51u + kz * 17u + ny];
        int t16 = (ky * ny) & 15;
        float c = C16c[t16], sn = S16c[t16];
        re += vv.x * c + vv.y * sn;
        im += vv.y * c - vv.x * sn;
      }
      g2[((size_t)tid * 16u + px) * 256u + bc] = make_float2(re, im);
    }
  } else {
    // weight transpose: wb = (kc, i); NT both ways, bf16-packed output
    f32x4* lw4 = (f32x4*)smem;
    float2* lw2 = (float2*)smem;
    unsigned wb = blockIdx.x - 4096u;
    unsigned kc = wb >> 6, i = wb & 63u;
    const f32x4* src = (const f32x4*)(w2 + ((size_t)kc * 64u + i) * 1728u);
    for (unsigned t = tid; t < 864u; t += 256u)
      lw4[t] = __builtin_nontemporal_load(src + t);
    __syncthreads();
    unsigned* dst = wtu + (size_t)kc * 110592u + (size_t)i * 64u;
    for (unsigned t = tid; t < 1728u; t += 256u) {
      unsigned f = t >> 6, o = t & 63u;
      float2 v = lw2[o * 27u + f];
      unsigned pk = ((unsigned)f2bf(v.y) << 16) | (unsigned)f2bf(v.x);
      __builtin_nontemporal_store(pk, dst + (size_t)f * 4096u + o);
    }
  }
}

// ---------------------------------------------------------------------------
// K2: x-DFT + per-frequency channel mix. WG = (kc, f); 256 thr.
__global__ __launch_bounds__(256) void k2_mix(const unsigned* __restrict__ wtu,
                                              const float2* __restrict__ g2,
                                              float2* __restrict__ oh2) {
  __shared__ float2 inl[256];
  unsigned tid = threadIdx.x;
  unsigned f = blockIdx.x % 27u;
  unsigned kc = blockIdx.x / 27u;
  unsigned k = kc >> 2, corner = kc & 3u;
  unsigned kz = f % 3u, kyl = (f / 3u) % 3u, kxl = f / 9u;
  unsigned kxi = kxl + 3u * (corner & 1u);
  unsigned kyi = kyl + 3u * (corner >> 1);
  unsigned fg = kxi * 18u + kyi * 3u + kz;
  unsigned row = k * 18u + kyi * 3u + kz;
  {  // Phase A: x-DFT for bc = tid; g2 read coalesced (2KB/wave-instr)
    const float2* gp = g2 + (size_t)row * 4096u + tid;
    int kx = KYv[kxi];
    float re = 0.f, im = 0.f;
#pragma unroll
    for (int nx = 0; nx < 16; nx++) {
      float2 vv = gp[nx * 256];
      int t16 = (kx * nx) & 15;
      float c = C16c[t16], sn = S16c[t16];
      re += vv.x * c + vv.y * sn;
      im += vv.y * c - vv.x * sn;
    }
    inl[tid] = make_float2(re, im);
  }
  __syncthreads();
  unsigned b = tid >> 6, o = tid & 63u;
  const unsigned* wp = wtu + ((size_t)kc * 27u + f) * 4096u + o;
  float2 acc = make_float2(0.f, 0.f);
#pragma unroll 16
  for (unsigned i = 0; i < 64u; i++) {
    float2 a = inl[(b << 6) | i];
    unsigned pk = __builtin_nontemporal_load(wp + (size_t)i * 64u);
    float wr = bf2f((unsigned short)(pk & 0xFFFFu));
    float wi = bf2f((unsigned short)(pk >> 16));
    acc.x += a.x * wr - a.y * wi;
    acc.y += a.x * wi + a.y * wr;
  }
  oh2[((size_t)(b * 64u + o)) * 864u + k * 108u + fg] = acc;
}

// ---------------------------------------------------------------------------
// K3: fused inverse sparse DFT + synthesis. WG = (bo reversed, slab-pair).
// Normal x loads (re-install into LLC for next replay); NT out stores.
__global__ __launch_bounds__(256) void k3_invsynth(const float2* __restrict__ oh2,
                                                   const float* __restrict__ x,
                                                   float* __restrict__ out) {
  __shared__ float2 hh[864];          // [k][fg]
  __shared__ float2 gx[2][8][18];     // [sl][k][kyi*3+kz]
  __shared__ float2 uu[2][8][3][16];  // [sl][k][kz][ny]
  __shared__ float W[2][8][16][16];   // [sl][m][ny][nz]
  unsigned tid = threadIdx.x;
  unsigned sp = blockIdx.x & 7u;              // slab pair: nx = sp*2 + sl
  unsigned bo = 255u - (blockIdx.x >> 3);     // reversed for LLC locality
  for (unsigned i = tid; i < 864u; i += 256u)
    hh[i] = oh2[(size_t)bo * 864u + i];
  __syncthreads();
  for (unsigned i = tid; i < 288u; i += 256u) {  // x-inverse (both slabs)
    unsigned sl = i / 144u, j = i - sl * 144u;
    unsigned k = j / 18u, r = j - k * 18u;
    unsigned nx = sp * 2u + sl;
    float re = 0.f, im = 0.f;
#pragma unroll
    for (int kxi = 0; kxi < 6; kxi++) {
      float2 v = hh[k * 108u + kxi * 18 + r];
      int t16 = (KYv[kxi] * (int)nx) & 15;
      float c = C16c[t16], sn = S16c[t16];
      re += v.x * c - v.y * sn;
      im += v.x * sn + v.y * c;
    }
    gx[sl][k][r] = make_float2(re, im);
  }
  __syncthreads();
  for (unsigned i = tid; i < 768u; i += 256u) {  // y-inverse
    unsigned sl = i / 384u, j = i - sl * 384u;
    unsigned k = j / 48u, rem = j - k * 48u;
    unsigned kz = rem >> 4, ny = rem & 15u;
    float re = 0.f, im = 0.f;
#pragma unroll
    for (int kyi = 0; kyi < 6; kyi++) {
      float2 v = gx[sl][k][kyi * 3 + kz];
      int t16 = (KYv[kyi] * (int)ny) & 15;
      float c = C16c[t16], sn = S16c[t16];
      re += v.x * c - v.y * sn;
      im += v.x * sn + v.y * c;
    }
    uu[sl][k][kz][ny] = make_float2(re, im);
  }
  __syncthreads();
  for (unsigned i = tid; i < 512u; i += 256u) {  // z-inverse + Hadamard
    unsigned sl = i >> 8, ny = (i >> 4) & 15u, nz = i & 15u;
    float c1 = C16c[nz], s1 = S16c[nz];
    int t2 = (2 * nz) & 15;
    float c2 = C16c[t2], s2 = S16c[t2];
    float val[8];
#pragma unroll
    for (int k = 0; k < 8; k++) {
      float2 u0 = uu[sl][k][0][ny], u1 = uu[sl][k][1][ny], u2 = uu[sl][k][2][ny];
      val[k] = (u0.x + 2.f * (u1.x * c1 - u1.y * s1) + 2.f * (u2.x * c2 - u2.y * s2)) * (1.f / 4096.f);
    }
#pragma unroll
    for (int st = 1; st < 8; st <<= 1)
#pragma unroll
      for (int i2 = 0; i2 < 8; i2++)
        if (!(i2 & st)) {
          float a = val[i2], b = val[i2 | st];
          val[i2] = a + b;
          val[i2 | st] = a - b;
        }
#pragma unroll
    for (int m = 0; m < 8; m++) W[sl][m][ny][nz] = val[m];
  }
  __syncthreads();
  unsigned w = tid >> 6, l = tid & 63u;
  unsigned z4 = l & 15u, y2 = l >> 4;
  unsigned mmy = ((y2 >> 1) & 1u) << 1;
  const float* xp = x + ((size_t)bo << 18);
  float* op = out + ((size_t)bo << 18);
#pragma unroll
  for (unsigned sl = 0; sl < 2u; ++sl) {
#pragma unroll
    for (unsigned r2 = 0; r2 < 8u; ++r2) {
      unsigned xp2 = r2 & 1u, yg = r2 >> 1;
      unsigned X0 = ((sp * 2u + sl) << 2) + (xp2 << 1);
      unsigned Y = (yg << 4) + (w << 2) + y2;
      size_t off = ((size_t)X0 << 12) + (Y << 6) + (z4 << 2);
      f32x4 v0 = *(const f32x4*)(xp + off);
      f32x4 v1 = *(const f32x4*)(xp + off + 4096u);
      float h0 = v0.x + v0.y + v1.x + v1.y;
      float h1 = v0.z + v0.w + v1.z + v1.w;
      float m0 = (h0 + __shfl_xor(h0, 16)) * 0.125f;
      float m1 = (h1 + __shfl_xor(h1, 16)) * 0.125f;
      unsigned ny = (yg << 2) + w;
      unsigned mm = (xp2 << 2) | mmy;
      float c0 = 0.125f * W[sl][mm][ny][z4] - m0;
      float c1 = 0.125f * W[sl][mm | 1u][ny][z4] - m1;
      v0.x += c0; v0.y += c0; v0.z += c1; v0.w += c1;
      v1.x += c0; v1.y += c0; v1.z += c1; v1.w += c1;
      __builtin_nontemporal_store(v0, (f32x4*)(op + off));
      __builtin_nontemporal_store(v1, (f32x4*)(op + off + 4096u));
    }
  }
}

extern "C" void kernel_launch(void* const* d_in, const int* in_sizes, int n_in,
                              void* d_out, int out_size, void* d_ws, size_t ws_size,
                              hipStream_t stream) {
  const float* x = (const float*)d_in[0];
  const float* w = (const float*)d_in[1];
  float* out = (float*)d_out;

  const size_t G_F2 = 144ull * 4096;        // 4.72 MB
  const size_t WT_U = 32ull * 27 * 4096;    // 3.54M u32 = 14.2 MB
  const size_t OH_F2 = 256ull * 864;        // 1.77 MB
  const size_t G_B = G_F2 * 8, WT_B = WT_U * 4, OH_B = OH_F2 * 8;

  float2 *g2, *oh2;
  unsigned* wtu;
  char* ws = (char*)d_ws;
  if (ws_size >= G_B + WT_B + OH_B) {
    g2 = (float2*)ws;
    wtu = (unsigned*)(ws + G_B);
    oh2 = (float2*)(ws + G_B + WT_B);
  } else {
    // d_out doubles as dead scratch for g2/wt (consumed before K3 overwrites
    // d_out). oh2 must survive into K3 -> keep in ws (needs 1.77 MB).
    g2 = (float2*)d_out;
    wtu = (unsigned*)((char*)d_out + G_B);
    oh2 = (float2*)ws;
  }

  k1_front_wtr<<<6144, 256, 0, stream>>>(x, (const float2*)w, g2, wtu);
  k2_mix<<<864, 256, 0, stream>>>(wtu, g2, oh2);
  k3_invsynth<<<2048, 256, 0, stream>>>(oh2, x, out);
}